// Round 14
// baseline (545.284 us; speedup 1.0000x reference)
//
#include <hip/hip_runtime.h>

#define TLEN  1024
#define HN    64
#define LOG2E 1.4426950408889634f

// clang builtins use __fp16 vectors, NOT _Float16.
typedef __fp16 half2v __attribute__((ext_vector_type(2)));

// One wave / batch element, 1024 blocks. hh matvec via v_pk_fma_f16.
//
// Unified issue model (fits R3/R7/R11/R12/R13): wall = total issue cycles
// + unhidable tail. fdot2 = 4cy issue; MFMA issue BLOCKS at pipe rate
// (~17cy) so nothing hides under it from one wave (R13 interleave null).
// Useful-MAC/issue-cy: MFMA 512/17~=30, fdot2 128/4=32 -- a tie, which is
// why R3 (524us) ~= R11 (508us). v_pk_fma_f16 is full-rate VALU (VOP3P,
// no cross-lane reduce; m07: plain fma = 2cy): 2 MAC/lane/2cy = 64/cy,
// 2x both. hh issue: 544 -> ~300 cy/step.
//
// Structure (all pieces verified in passing rounds):
//  * h-pairs {h[2P],h[2P+1]} from 8 uniform ds_read_b128 of hbuf
//    (conflict-free broadcast, R12) -- no readlanes (R3's 272cy), no
//    permutation gambles (R4-R6), no bpermute storm (R7).
//  * per gate 4 ROTATING half2 accumulators (slot = 8 products, f16
//    accum; gate-hh magnitude <=~1.5 so f16 eps ~1e-3 worst), combined
//    by 3 pk-adds + 2 cvt + f32 add into the gate value. x-dot + bias
//    stay f32 fdot2 (exact-ish, as all passing rounds).
//  * absmax will NOT be bit-identical (f16 accumulation): expect
//    ~1.5-3e-3 vs threshold 4.6e-3.
// Carried EXACTLY from R3: x staged 64 steps/chunk (coalesced 16B/lane,
// 2 readlane broadcasts/step, 64-step prefetch), pre-scaled f16 weights
// (log2e folded, 2*log2e tanh gate), exp2+rcp activations, FC ring[64][65]
// + epilogue outside the loop, h published f16 RTZ via ds_write_b16,
// hbuf WAR safe single-wave (in-order DS queue).

#define FOR32(X) \
    X(0) X(1) X(2) X(3) X(4) X(5) X(6) X(7) \
    X(8) X(9) X(10) X(11) X(12) X(13) X(14) X(15) \
    X(16) X(17) X(18) X(19) X(20) X(21) X(22) X(23) \
    X(24) X(25) X(26) X(27) X(28) X(29) X(30) X(31)

// pair P -> q-register (P/4), component (P%4), accumulator (P%4)
#define FORPQ(X) \
    X(0,q0,x,0)  X(1,q0,y,1)  X(2,q0,z,2)  X(3,q0,w,3) \
    X(4,q1,x,0)  X(5,q1,y,1)  X(6,q1,z,2)  X(7,q1,w,3) \
    X(8,q2,x,0)  X(9,q2,y,1)  X(10,q2,z,2) X(11,q2,w,3) \
    X(12,q3,x,0) X(13,q3,y,1) X(14,q3,z,2) X(15,q3,w,3) \
    X(16,q4,x,0) X(17,q4,y,1) X(18,q4,z,2) X(19,q4,w,3) \
    X(20,q5,x,0) X(21,q5,y,1) X(22,q5,z,2) X(23,q5,w,3) \
    X(24,q6,x,0) X(25,q6,y,1) X(26,q6,z,2) X(27,q6,w,3) \
    X(28,q7,x,0) X(29,q7,y,1) X(30,q7,z,2) X(31,q7,w,3)

__global__ __launch_bounds__(64, 1)
void lstm_pk(const float* __restrict__ x,      // [B, T, 4]
             const float* __restrict__ W_ih,   // [256, 4]
             const float* __restrict__ W_hh,   // [256, 64]
             const float* __restrict__ b_ih,   // [256]
             const float* __restrict__ b_hh,   // [256]
             const float* __restrict__ W_fc,   // [1, 64]
             const float* __restrict__ b_fc,   // [1]
             float* __restrict__ out)          // [B, T]
{
    const int b = blockIdx.x;
    const int l = threadIdx.x;   // lane == hidden unit

    __shared__ float ring[64][65];                    // FC partials
    __shared__ alignas(16) unsigned short hbuf[HN];   // h_t as f16

    hbuf[l] = 0;   // h_0 = 0 (single wave: in-order DS queue)

    const float* wr_i = W_hh + (0 * HN + l) * HN;
    const float* wr_f = W_hh + (1 * HN + l) * HN;
    const float* wr_g = W_hh + (2 * HN + l) * HN;
    const float* wr_o = W_hh + (3 * HN + l) * HN;

    // ---- 128 half2 weight pairs {w[2P], w[2P+1]}, pre-scaled, pinned ----
#define DECLP(P) half2v pi##P, pf##P, pg##P, po##P;
    FOR32(DECLP)
#undef DECLP

#define LOADP(P) \
    pi##P = __builtin_amdgcn_cvt_pkrtz(wr_i[2 * (P)] * LOG2E, \
                                       wr_i[2 * (P) + 1] * LOG2E); \
    pf##P = __builtin_amdgcn_cvt_pkrtz(wr_f[2 * (P)] * LOG2E, \
                                       wr_f[2 * (P) + 1] * LOG2E); \
    pg##P = __builtin_amdgcn_cvt_pkrtz(wr_g[2 * (P)] * (2.0f * LOG2E), \
                                       wr_g[2 * (P) + 1] * (2.0f * LOG2E)); \
    po##P = __builtin_amdgcn_cvt_pkrtz(wr_o[2 * (P)] * LOG2E, \
                                       wr_o[2 * (P) + 1] * LOG2E); \
    asm volatile("" : "+v"(pi##P), "+v"(pf##P), "+v"(pg##P), "+v"(po##P));
    FOR32(LOADP)
#undef LOADP

    // ---- x-weights (unit l), pre-scaled; 2 half2 per gate (as R3) ----
    half2v wip0 = __builtin_amdgcn_cvt_pkrtz(W_ih[(0 * HN + l) * 4 + 0] * LOG2E,
                                             W_ih[(0 * HN + l) * 4 + 1] * LOG2E);
    half2v wip1 = __builtin_amdgcn_cvt_pkrtz(W_ih[(0 * HN + l) * 4 + 2] * LOG2E,
                                             W_ih[(0 * HN + l) * 4 + 3] * LOG2E);
    half2v wfp0 = __builtin_amdgcn_cvt_pkrtz(W_ih[(1 * HN + l) * 4 + 0] * LOG2E,
                                             W_ih[(1 * HN + l) * 4 + 1] * LOG2E);
    half2v wfp1 = __builtin_amdgcn_cvt_pkrtz(W_ih[(1 * HN + l) * 4 + 2] * LOG2E,
                                             W_ih[(1 * HN + l) * 4 + 3] * LOG2E);
    half2v wgp0 = __builtin_amdgcn_cvt_pkrtz(W_ih[(2 * HN + l) * 4 + 0] * 2.0f * LOG2E,
                                             W_ih[(2 * HN + l) * 4 + 1] * 2.0f * LOG2E);
    half2v wgp1 = __builtin_amdgcn_cvt_pkrtz(W_ih[(2 * HN + l) * 4 + 2] * 2.0f * LOG2E,
                                             W_ih[(2 * HN + l) * 4 + 3] * 2.0f * LOG2E);
    half2v wop0 = __builtin_amdgcn_cvt_pkrtz(W_ih[(3 * HN + l) * 4 + 0] * LOG2E,
                                             W_ih[(3 * HN + l) * 4 + 1] * LOG2E);
    half2v wop1 = __builtin_amdgcn_cvt_pkrtz(W_ih[(3 * HN + l) * 4 + 2] * LOG2E,
                                             W_ih[(3 * HN + l) * 4 + 3] * LOG2E);

    const float bias_i = (b_ih[0 * HN + l] + b_hh[0 * HN + l]) * LOG2E;
    const float bias_f = (b_ih[1 * HN + l] + b_hh[1 * HN + l]) * LOG2E;
    const float bias_g = (b_ih[2 * HN + l] + b_hh[2 * HN + l]) * (2.0f * LOG2E);
    const float bias_o = (b_ih[3 * HN + l] + b_hh[3 * HN + l]) * LOG2E;
    const float wfc = W_fc[l];
    const float bfc = b_fc[0];

    const float* xb = x   + (size_t)b * TLEN * 4;
    float*       ob = out + (size_t)b * TLEN;

    float h = 0.0f, c = 0.0f;
    const half2v zh = {(__fp16)0.0f, (__fp16)0.0f};

    // ---- x stage: lane l holds x[t0 + l] (16B coalesced per chunk) ----
    float4 xcur = *(const float4*)(xb + (size_t)l * 4);   // chunk 0

    for (int ci = 0; ci < TLEN / 64; ++ci) {
        const int cn = (ci < TLEN / 64 - 1) ? ci + 1 : ci;
        float4 xnext = *(const float4*)(xb + (size_t)(cn * 64 + l) * 4);

        const int xq0 = __builtin_bit_cast(int, __builtin_amdgcn_cvt_pkrtz(xcur.x, xcur.y));
        const int xq1 = __builtin_bit_cast(int, __builtin_amdgcn_cvt_pkrtz(xcur.z, xcur.w));

        for (int s = 0; s < 64; ++s) {
            // ---- h pairs: 8 uniform b128 reads (broadcast, no conflicts)
            const uint4 q0 = *(const uint4*)&hbuf[0];
            const uint4 q1 = *(const uint4*)&hbuf[8];
            const uint4 q2 = *(const uint4*)&hbuf[16];
            const uint4 q3 = *(const uint4*)&hbuf[24];
            const uint4 q4 = *(const uint4*)&hbuf[32];
            const uint4 q5 = *(const uint4*)&hbuf[40];
            const uint4 q6 = *(const uint4*)&hbuf[48];
            const uint4 q7 = *(const uint4*)&hbuf[56];

            // ---- x broadcast + f32 x-dot chains (hide the LDS latency) --
            const int xi0 = __builtin_amdgcn_readlane(xq0, s);
            const int xi1 = __builtin_amdgcn_readlane(xq1, s);
            const half2v xh0 = __builtin_bit_cast(half2v, xi0);
            const half2v xh1 = __builtin_bit_cast(half2v, xi1);

            float ai = __builtin_amdgcn_fdot2(wip0, xh0, bias_i, false);
            float af = __builtin_amdgcn_fdot2(wfp0, xh0, bias_f, false);
            float ag = __builtin_amdgcn_fdot2(wgp0, xh0, bias_g, false);
            float ao = __builtin_amdgcn_fdot2(wop0, xh0, bias_o, false);
            ai = __builtin_amdgcn_fdot2(wip1, xh1, ai, false);
            af = __builtin_amdgcn_fdot2(wfp1, xh1, af, false);
            ag = __builtin_amdgcn_fdot2(wgp1, xh1, ag, false);
            ao = __builtin_amdgcn_fdot2(wop1, xh1, ao, false);

            // ---- hh matvec: 128 v_pk_fma_f16, 4 rotating accs/gate ----
            half2v ci0 = zh, ci1 = zh, ci2 = zh, ci3 = zh;
            half2v cf0 = zh, cf1 = zh, cf2 = zh, cf3 = zh;
            half2v cg0 = zh, cg1 = zh, cg2 = zh, cg3 = zh;
            half2v co0 = zh, co1 = zh, co2 = zh, co3 = zh;

#define MACP(P, Q, C, A) { \
            const half2v hp = __builtin_bit_cast(half2v, (int)(Q).C); \
            ci##A = pi##P * hp + ci##A; \
            cf##A = pf##P * hp + cf##A; \
            cg##A = pg##P * hp + cg##A; \
            co##A = po##P * hp + co##A; }
            FORPQ(MACP)
#undef MACP

            // ---- combine: 3 pk-adds -> 1 half2 -> f32 (per gate) ----
            {
                const half2v sI = (ci0 + ci1) + (ci2 + ci3);
                ai += (float)sI[0] + (float)sI[1];
                const half2v sF = (cf0 + cf1) + (cf2 + cf3);
                af += (float)sF[0] + (float)sF[1];
                const half2v sG = (cg0 + cg1) + (cg2 + cg3);
                ag += (float)sG[0] + (float)sG[1];
                const half2v sO = (co0 + co1) + (co2 + co3);
                ao += (float)sO[0] + (float)sO[1];
            }

            // ---- activations (pre-scaled): sigmoid/tanh via exp2+rcp ----
            float si = __builtin_amdgcn_rcpf(1.0f + __builtin_amdgcn_exp2f(-ai));
            float sf = __builtin_amdgcn_rcpf(1.0f + __builtin_amdgcn_exp2f(-af));
            float tg = 1.0f - 2.0f * __builtin_amdgcn_rcpf(
                                         1.0f + __builtin_amdgcn_exp2f(ag));
            float so = __builtin_amdgcn_rcpf(1.0f + __builtin_amdgcn_exp2f(-ao));

            c = sf * c + si * tg;
            float th = 1.0f - 2.0f * __builtin_amdgcn_rcpf(
                           1.0f + __builtin_amdgcn_exp2f(c * (2.0f * LOG2E)));
            h = so * th;

            // ---- publish h (f16 RTZ) + FC partial ----
            const int hpk = __builtin_bit_cast(int,
                                __builtin_amdgcn_cvt_pkrtz(h, h));
            hbuf[l] = (unsigned short)(hpk & 0xffff);
            ring[s][l] = h * wfc;
        }

        // ---- FC: transposed reduce + coalesced 64-wide store ----
        __syncthreads();   // single wave: orders LDS w->r
        float s0 = 0.f, s1 = 0.f, s2 = 0.f, s3 = 0.f;
#pragma unroll
        for (int k = 0; k < HN; k += 4) {
            s0 += ring[l][k];
            s1 += ring[l][k + 1];
            s2 += ring[l][k + 2];
            s3 += ring[l][k + 3];
        }
        ob[ci * 64 + l] = (s0 + s1) + (s2 + s3) + bfc;

        xcur = xnext;
    }
}

extern "C" void kernel_launch(void* const* d_in, const int* in_sizes, int n_in,
                              void* d_out, int out_size, void* d_ws, size_t ws_size,
                              hipStream_t stream) {
    const float* x    = (const float*)d_in[0];
    const float* W_ih = (const float*)d_in[1];
    const float* W_hh = (const float*)d_in[2];
    const float* b_ih = (const float*)d_in[3];
    const float* b_hh = (const float*)d_in[4];
    const float* W_fc = (const float*)d_in[5];
    const float* b_fc = (const float*)d_in[6];
    float* out = (float*)d_out;

    const int B = in_sizes[0] / (TLEN * 4);   // 1024
    lstm_pk<<<dim3(B), dim3(64), 0, stream>>>(
        x, W_ih, W_hh, b_ih, b_hh, W_fc, b_fc, out);
}